// Round 2
// baseline (508.482 us; speedup 1.0000x reference)
//
#include <hip/hip_runtime.h>
#include <stdint.h>

#define BB 32
#define CC 2048
#define NPIX 49
#define KPAD 64
#define K9 18432      // CC*9
#define NCOLP 1664    // 13*128 (N=1568 padded)
#define SPLITK 4
#define KCHUNK 4608   // K9/SPLITK

typedef __bf16 bf16;
typedef __bf16 bf16x8 __attribute__((ext_vector_type(8)));
typedef float f32x4 __attribute__((ext_vector_type(4)));
typedef uint32_t u32x4 __attribute__((ext_vector_type(4)));

#define MFMA(a,b,c) __builtin_amdgcn_mfma_f32_16x16x32_bf16(a,b,c,0,0,0)

// ---------- prep: x -> xb [B][C][64] bf16 (K padded 49->64 with zeros) ----------
__global__ void prep_xb_kernel(const float* __restrict__ x, bf16* __restrict__ xb) {
    uint32_t idx = blockIdx.x * 256u + threadIdx.x;   // [b*C+c][n]
    uint32_t n = idx & 63u, bc = idx >> 6;
    float v = (n < 49u) ? x[bc * 49u + n] : 0.f;
    xb[idx] = (bf16)v;
}

// ---------- prep: x -> xbT [B][64][C] bf16 ----------
__global__ void prep_xbT_kernel(const float* __restrict__ x, bf16* __restrict__ xbT) {
    uint32_t idx = blockIdx.x * 256u + threadIdx.x;   // [b][n][c]
    uint32_t c = idx & 2047u, n = (idx >> 11) & 63u, b = idx >> 17;
    float v = (n < 49u) ? x[(b * 2048u + c) * 49u + n] : 0.f;
    xbT[idx] = (bf16)v;
}

// ---------- prep: conv_w f32 -> wb bf16 [2048][18432] (layout identical, pure cast) ----------
__global__ void cast_w_kernel(const float* __restrict__ cw, bf16* __restrict__ wb) {
    uint32_t t = blockIdx.x * 256u + threadIdx.x;
    uint32_t base = t * 8u;
    bf16x8 v;
#pragma unroll
    for (int i = 0; i < 8; i++) v[i] = (bf16)cw[base + i];
    *(bf16x8*)(wb + base) = v;
}

// ---------- prep: zero Yp [B][C][9][9] bf16 ----------
__global__ void zero_yp_kernel(u32x4* __restrict__ Yp) {
    Yp[blockIdx.x * 256u + threadIdx.x] = (u32x4){0, 0, 0, 0};
}

// ---------- fused bilinear -> softmax -> Y  (flash-style, no max needed: scores in [-2.2,0.9]) ----------
// grid: 512 blocks = b(32) x cblk(16).  4 waves, each wave owns 32 c-rows.
__global__ __launch_bounds__(256, 2) void attn_kernel(
    const bf16* __restrict__ xb, const bf16* __restrict__ xbT, bf16* __restrict__ Yp)
{
    __shared__ bf16 Plds[4][32][136];   // per-wave private P tile rows (pad 136: 272B row = 2-way-free banks)
    const int tid = threadIdx.x;
    const int w = tid >> 6, l = tid & 63;
    const int lhi = l >> 4, llo = l & 15;
    const int b = blockIdx.x >> 4, cblk = blockIdx.x & 15;
    const int c0 = cblk * 128 + w * 32;
    const bf16* xbB = xb + (size_t)b * CC * KPAD;
    const bf16* xbTB = xbT + (size_t)b * KPAD * CC;

    // hoist A-frags (this wave's 32 c-rows), invariant over d-tiles
    bf16x8 aQ[2][2];
#pragma unroll
    for (int cf = 0; cf < 2; cf++)
#pragma unroll
        for (int kk = 0; kk < 2; kk++)
            aQ[cf][kk] = *(const bf16x8*)(xbB + (uint32_t)(c0 + cf * 16 + llo) * KPAD + kk * 32 + lhi * 8);

    f32x4 accY[2][4];
#pragma unroll
    for (int cf = 0; cf < 2; cf++)
#pragma unroll
        for (int nf = 0; nf < 4; nf++) accY[cf][nf] = (f32x4){0, 0, 0, 0};
    float rowsum[2][4] = {};

    for (int dt = 0; dt < 16; dt++) {
        const int d0 = dt * 128;
        f32x4 accS[2][8];
#pragma unroll
        for (int cf = 0; cf < 2; cf++)
#pragma unroll
            for (int df = 0; df < 8; df++) accS[cf][df] = (f32x4){0, 0, 0, 0};
        // S = Xc . Xd^T  (K = 64 padded)
#pragma unroll
        for (int kk = 0; kk < 2; kk++) {
#pragma unroll
            for (int df = 0; df < 8; df++) {
                bf16x8 bK = *(const bf16x8*)(xbB + (uint32_t)(d0 + df * 16 + llo) * KPAD + kk * 32 + lhi * 8);
                accS[0][df] = MFMA(aQ[0][kk], bK, accS[0][df]);
                accS[1][df] = MFMA(aQ[1][kk], bK, accS[1][df]);
            }
        }
        // P = exp(-S/49); accumulate rowsum; relayout via wave-private LDS
#pragma unroll
        for (int cf = 0; cf < 2; cf++)
#pragma unroll
            for (int df = 0; df < 8; df++)
#pragma unroll
                for (int r = 0; r < 4; r++) {
                    float p = __expf(accS[cf][df][r] * (-1.0f / 49.0f));
                    rowsum[cf][r] += p;
                    Plds[w][cf * 16 + lhi * 4 + r][df * 16 + llo] = (bf16)p;
                }
        __syncthreads();
        // Y += P . Xd   (K = 128 over d)
#pragma unroll
        for (int kk2 = 0; kk2 < 4; kk2++) {
            bf16x8 aP[2];
#pragma unroll
            for (int cf = 0; cf < 2; cf++)
                aP[cf] = *(const bf16x8*)&Plds[w][cf * 16 + llo][kk2 * 32 + lhi * 8];
#pragma unroll
            for (int nf = 0; nf < 4; nf++) {
                bf16x8 bV = *(const bf16x8*)(xbTB + (uint32_t)(nf * 16 + llo) * CC + d0 + kk2 * 32 + lhi * 8);
                accY[0][nf] = MFMA(aP[0], bV, accY[0][nf]);
                accY[1][nf] = MFMA(aP[1], bV, accY[1][nf]);
            }
        }
        __syncthreads();
    }
    // rowsum: reduce across the 16 lanes sharing lhi (cols), then normalize + store
#pragma unroll
    for (int cf = 0; cf < 2; cf++)
#pragma unroll
        for (int r = 0; r < 4; r++) {
            float s = rowsum[cf][r];
            s += __shfl_xor(s, 1);
            s += __shfl_xor(s, 2);
            s += __shfl_xor(s, 4);
            s += __shfl_xor(s, 8);
            rowsum[cf][r] = 1.0f / s;
        }
#pragma unroll
    for (int cf = 0; cf < 2; cf++)
#pragma unroll
        for (int nf = 0; nf < 4; nf++)
#pragma unroll
            for (int r = 0; r < 4; r++) {
                int n = nf * 16 + llo;
                if (n < NPIX) {
                    int c = c0 + cf * 16 + lhi * 4 + r;
                    int i = n / 7, j = n % 7;
                    Yp[((size_t)(b * CC + c)) * 81 + (i + 1) * 9 + (j + 1)] =
                        (bf16)(accY[cf][nf][r] * rowsum[cf][r]);
                }
            }
}

// ---------- im2col: Yp -> bmatT [NCOLP][K9] bf16 (rows n>=1568 zeroed) ----------
__global__ void im2col_kernel(const bf16* __restrict__ Yp, bf16* __restrict__ bmat) {
    uint32_t idx = blockIdx.x * 256u + threadIdx.x;   // n*K9 + k
    uint32_t k = idx % 18432u;
    uint32_t n = idx / 18432u;
    bf16 v = (bf16)0.f;
    if (n < 1568u) {
        uint32_t bq = n / 49u, p = n % 49u;
        uint32_t i = p / 7u, j = p % 7u;
        uint32_t ci = k / 9u, t = k % 9u;
        uint32_t di = t / 3u, dj = t % 3u;
        v = Yp[(size_t)(bq * 2048u + ci) * 81u + (i + di) * 9u + (j + dj)];
    }
    bmat[idx] = v;
}

// ---------- conv GEMM: M=2048, N=1664, K=18432, split-K=4, m97 structure ----------
__global__ __launch_bounds__(256, 2) void conv_kernel(
    const bf16* __restrict__ wb, const bf16* __restrict__ bmat, float* __restrict__ partials)
{
    __shared__ bf16 Asub[128 * 64];
    __shared__ bf16 Bsub[128 * 64];
    const int tid = threadIdx.x;
    const int w = tid >> 6, l = tid & 63;
    const int lhi = l >> 4, llo = l & 15;
    const uint32_t bx = blockIdx.x;
    const uint32_t nt = bx % 13u;
    const uint32_t mt = (bx / 13u) & 15u;
    const uint32_t z = bx / 208u;
    const int wm = w >> 1, wn = w & 1;

    f32x4 acc[4][4];
#pragma unroll
    for (int fm = 0; fm < 4; fm++)
#pragma unroll
        for (int fn = 0; fn < 4; fn++) acc[fm][fn] = (f32x4){0, 0, 0, 0};

    const int flatA = w * 4096;                       // this wave's byte quarter of the 16KB tile
    const uint32_t eo0 = (uint32_t)(flatA + l * 16) >> 1;

    for (int kt = 0; kt < 72; kt++) {
        const uint32_t kb = z * KCHUNK + (uint32_t)kt * 64u;
#pragma unroll
        for (int i = 0; i < 4; i++) {
            uint32_t eo = eo0 + (uint32_t)i * 512u;
            uint32_t row = eo >> 6, col = eo & 63u;
            const bf16* ga = wb + (size_t)(mt * 128u + row) * K9 + kb + col;
            const bf16* gb = bmat + (size_t)(nt * 128u + row) * K9 + kb + col;
            __builtin_amdgcn_global_load_lds((const __attribute__((address_space(1))) void*)ga,
                (__attribute__((address_space(3))) void*)((char*)Asub + flatA + i * 1024), 16, 0, 0);
            __builtin_amdgcn_global_load_lds((const __attribute__((address_space(1))) void*)gb,
                (__attribute__((address_space(3))) void*)((char*)Bsub + flatA + i * 1024), 16, 0, 0);
        }
        __syncthreads();
#pragma unroll
        for (int kk = 0; kk < 2; kk++) {
            bf16x8 af[4], bfr[4];
#pragma unroll
            for (int f = 0; f < 4; f++)
                af[f] = *(const bf16x8*)&Asub[(wm * 64 + f * 16 + llo) * 64 + kk * 32 + lhi * 8];
#pragma unroll
            for (int f = 0; f < 4; f++)
                bfr[f] = *(const bf16x8*)&Bsub[(wn * 64 + f * 16 + llo) * 64 + kk * 32 + lhi * 8];
#pragma unroll
            for (int fm = 0; fm < 4; fm++)
#pragma unroll
                for (int fn = 0; fn < 4; fn++)
                    acc[fm][fn] = MFMA(af[fm], bfr[fn], acc[fm][fn]);
        }
        __syncthreads();
    }
    float* pz = partials + (size_t)z * CC * NCOLP;
#pragma unroll
    for (int fm = 0; fm < 4; fm++)
#pragma unroll
        for (int fn = 0; fn < 4; fn++)
#pragma unroll
            for (int r = 0; r < 4; r++) {
                uint32_t m = mt * 128u + (uint32_t)(wm * 64 + fm * 16 + lhi * 4 + r);
                uint32_t n = nt * 128u + (uint32_t)(wn * 64 + fn * 16 + llo);
                pz[(size_t)m * NCOLP + n] = acc[fm][fn][r];
            }
}

// ---------- reduce: out = sum_z partials + bias + residual ----------
__global__ void reduce_kernel(const float* __restrict__ partials, const float* __restrict__ x,
                              const float* __restrict__ cb, float* __restrict__ out)
{
    uint32_t idx = blockIdx.x * 256u + threadIdx.x;   // [b][c][p]
    uint32_t p = idx % 49u;
    uint32_t c = (idx / 49u) & 2047u;
    uint32_t b = idx / (49u * 2048u);
    size_t base = (size_t)c * NCOLP + b * 49u + p;
    float s = cb[c] + x[idx];
#pragma unroll
    for (int zz = 0; zz < SPLITK; zz++) s += partials[(size_t)zz * CC * NCOLP + base];
    out[idx] = s;
}

extern "C" void kernel_launch(void* const* d_in, const int* in_sizes, int n_in,
                              void* d_out, int out_size, void* d_ws, size_t ws_size,
                              hipStream_t stream) {
    (void)in_sizes; (void)n_in; (void)out_size; (void)ws_size;
    const float* x = (const float*)d_in[0];
    const float* cw = (const float*)d_in[1];
    const float* cb = (const float*)d_in[2];
    float* out = (float*)d_out;
    char* ws = (char*)d_ws;

    bf16* xb   = (bf16*)(ws);                    //  8,388,608 B
    bf16* xbT  = (bf16*)(ws + 8388608);          //  8,388,608 B
    bf16* wb   = (bf16*)(ws + 16777216);         // 75,497,472 B
    bf16* Yp   = (bf16*)(ws + 92274688);         // 10,616,832 B
    bf16* bmat = (bf16*)(ws + 102891520);        // 61,341,696 B
    float* partials = (float*)(ws + 164233216);  // 54,525,952 B  (total 218,759,168)

    prep_xb_kernel<<<16384, 256, 0, stream>>>(x, xb);
    prep_xbT_kernel<<<16384, 256, 0, stream>>>(x, xbT);
    cast_w_kernel<<<18432, 256, 0, stream>>>(cw, wb);
    zero_yp_kernel<<<2592, 256, 0, stream>>>((u32x4*)Yp);
    attn_kernel<<<512, 256, 0, stream>>>(xb, xbT, Yp);
    im2col_kernel<<<119808, 256, 0, stream>>>(Yp, bmat);
    conv_kernel<<<832, 256, 0, stream>>>(wb, bmat, partials);
    reduce_kernel<<<12544, 256, 0, stream>>>(partials, x, cb, out);
}

// Round 3
// 439.848 us; speedup vs baseline: 1.1560x; 1.1560x over previous
//
#include <hip/hip_runtime.h>
#include <stdint.h>

#define BB 32
#define CC 2048
#define NPIX 49
#define KPAD 64
#define K9 18432      // CC*9 (k = tap*2048 + ci, tap-major)

typedef __bf16 bf16;
typedef __bf16 bf16x4 __attribute__((ext_vector_type(4)));
typedef __bf16 bf16x8 __attribute__((ext_vector_type(8)));
typedef float f32x4 __attribute__((ext_vector_type(4)));
typedef uint32_t u32x4 __attribute__((ext_vector_type(4)));

#define MFMA(a,b,c) __builtin_amdgcn_mfma_f32_16x16x32_bf16(a,b,c,0,0,0)
#define GLOAD_LDS(g, l) __builtin_amdgcn_global_load_lds( \
    (const __attribute__((address_space(1))) void*)(g),   \
    (__attribute__((address_space(3))) void*)(l), 16, 0, 0)

// ---------- prep: x -> xb [B][C][64] bf16 (K padded 49->64 with zeros) ----------
__global__ void prep_xb_kernel(const float* __restrict__ x, bf16* __restrict__ xb) {
    uint32_t idx = blockIdx.x * 256u + threadIdx.x;
    uint32_t n = idx & 63u, bc = idx >> 6;
    float v = (n < 49u) ? x[bc * 49u + n] : 0.f;
    xb[idx] = (bf16)v;
}

// ---------- prep: x -> xbT [B][64][C] bf16 ----------
__global__ void prep_xbT_kernel(const float* __restrict__ x, bf16* __restrict__ xbT) {
    uint32_t idx = blockIdx.x * 256u + threadIdx.x;
    uint32_t c = idx & 2047u, n = (idx >> 11) & 63u, b = idx >> 17;
    float v = (n < 49u) ? x[(b * 2048u + c) * 49u + n] : 0.f;
    xbT[idx] = (bf16)v;
}

// ---------- prep: conv_w [co][ci][3][3] f32 -> Wr [co][t][ci] bf16 (tap-major K) ----------
// thread handles (co, ci0=4*q): reads 36 consecutive f32 (16B-aligned), writes 9x bf16x4.
__global__ void castw_kernel(const float* __restrict__ cw, bf16* __restrict__ Wr) {
    uint32_t t = blockIdx.x * 256u + threadIdx.x;   // 2048*512
    uint32_t q = t & 511u, co = t >> 9;
    uint32_t ci0 = q * 4u;
    const float* src = cw + ((size_t)co * 2048u + ci0) * 9u;
    float v[4][9];
#pragma unroll
    for (int c = 0; c < 4; c++)
#pragma unroll
        for (int tt = 0; tt < 9; tt++) v[c][tt] = src[c * 9 + tt];
    bf16* dst = Wr + (size_t)co * K9 + ci0;
#pragma unroll
    for (int tt = 0; tt < 9; tt++) {
        bf16x4 o;
        o[0] = (bf16)v[0][tt]; o[1] = (bf16)v[1][tt];
        o[2] = (bf16)v[2][tt]; o[3] = (bf16)v[3][tt];
        *(bf16x4*)(dst + (size_t)tt * 2048u) = o;
    }
}

// ---------- prep: zero YpT [B][81][C] bf16 (halo rows must be 0) ----------
__global__ void zero_ypt_kernel(u32x4* __restrict__ YpT) {
    YpT[blockIdx.x * 256u + threadIdx.x] = (u32x4){0, 0, 0, 0};
}

// ---------- fused bilinear -> softmax -> Y, writing YpT[b][sp][c] (transposed, padded) ----------
// grid: 512 blocks = b(32) x cblk(16). 4 waves, each wave owns 32 c-rows.
__global__ __launch_bounds__(256, 2) void attn_kernel(
    const bf16* __restrict__ xb, const bf16* __restrict__ xbT, bf16* __restrict__ YpT)
{
    __shared__ __align__(16) char smem_raw[34816];
    bf16 (*Plds)[32][136] = reinterpret_cast<bf16(*)[32][136]>(smem_raw);  // per-wave P tiles
    bf16 (*Tlds)[132]     = reinterpret_cast<bf16(*)[132]>(smem_raw);      // [64 n][128+4 c] transpose buf
    const int tid = threadIdx.x;
    const int w = tid >> 6, l = tid & 63;
    const int lhi = l >> 4, llo = l & 15;
    const int b = blockIdx.x >> 4, cblk = blockIdx.x & 15;
    const int c0 = cblk * 128 + w * 32;
    const bf16* xbB = xb + (size_t)b * CC * KPAD;
    const bf16* xbTB = xbT + (size_t)b * KPAD * CC;

    bf16x8 aQ[2][2];
#pragma unroll
    for (int cf = 0; cf < 2; cf++)
#pragma unroll
        for (int kk = 0; kk < 2; kk++)
            aQ[cf][kk] = *(const bf16x8*)(xbB + (uint32_t)(c0 + cf * 16 + llo) * KPAD + kk * 32 + lhi * 8);

    f32x4 accY[2][4];
#pragma unroll
    for (int cf = 0; cf < 2; cf++)
#pragma unroll
        for (int nf = 0; nf < 4; nf++) accY[cf][nf] = (f32x4){0, 0, 0, 0};
    float rowsum[2][4] = {};

    for (int dt = 0; dt < 16; dt++) {
        const int d0 = dt * 128;
        f32x4 accS[2][8];
#pragma unroll
        for (int cf = 0; cf < 2; cf++)
#pragma unroll
            for (int df = 0; df < 8; df++) accS[cf][df] = (f32x4){0, 0, 0, 0};
#pragma unroll
        for (int kk = 0; kk < 2; kk++) {
#pragma unroll
            for (int df = 0; df < 8; df++) {
                bf16x8 bK = *(const bf16x8*)(xbB + (uint32_t)(d0 + df * 16 + llo) * KPAD + kk * 32 + lhi * 8);
                accS[0][df] = MFMA(aQ[0][kk], bK, accS[0][df]);
                accS[1][df] = MFMA(aQ[1][kk], bK, accS[1][df]);
            }
        }
#pragma unroll
        for (int cf = 0; cf < 2; cf++)
#pragma unroll
            for (int df = 0; df < 8; df++)
#pragma unroll
                for (int r = 0; r < 4; r++) {
                    float p = __expf(accS[cf][df][r] * (-1.0f / 49.0f));
                    rowsum[cf][r] += p;
                    Plds[w][cf * 16 + lhi * 4 + r][df * 16 + llo] = (bf16)p;
                }
        __syncthreads();
#pragma unroll
        for (int kk2 = 0; kk2 < 4; kk2++) {
            bf16x8 aP[2];
#pragma unroll
            for (int cf = 0; cf < 2; cf++)
                aP[cf] = *(const bf16x8*)&Plds[w][cf * 16 + llo][kk2 * 32 + lhi * 8];
#pragma unroll
            for (int nf = 0; nf < 4; nf++) {
                bf16x8 bV = *(const bf16x8*)(xbTB + (uint32_t)(nf * 16 + llo) * CC + d0 + kk2 * 32 + lhi * 8);
                accY[0][nf] = MFMA(aP[0], bV, accY[0][nf]);
                accY[1][nf] = MFMA(aP[1], bV, accY[1][nf]);
            }
        }
        __syncthreads();
    }
    // rowsum reduce across the 16 lanes holding one row's 16 col-chunks
#pragma unroll
    for (int cf = 0; cf < 2; cf++)
#pragma unroll
        for (int r = 0; r < 4; r++) {
            float s = rowsum[cf][r];
            s += __shfl_xor(s, 1);
            s += __shfl_xor(s, 2);
            s += __shfl_xor(s, 4);
            s += __shfl_xor(s, 8);
            rowsum[cf][r] = 1.0f / s;
        }
    // write normalized Y into Tlds[n][c_local] (bf16), then coalesced store to YpT
#pragma unroll
    for (int cf = 0; cf < 2; cf++)
#pragma unroll
        for (int nf = 0; nf < 4; nf++)
#pragma unroll
            for (int r = 0; r < 4; r++) {
                int n = nf * 16 + llo;
                int cl = w * 32 + cf * 16 + lhi * 4 + r;
                Tlds[n][cl] = (bf16)(accY[cf][nf][r] * rowsum[cf][r]);
            }
    __syncthreads();
    // 49 interior rows -> YpT[b][(i+1)*9+(j+1)][cblk*128 + 0..128), 4B/lane coalesced
#pragma unroll
    for (int rr = 0; rr < 13; rr++) {
        int row = rr * 4 + (tid >> 6);
        if (row < NPIX) {
            int i = row / 7, j = row % 7;
            int sp = (i + 1) * 9 + (j + 1);
            int col2 = tid & 63;                       // 2 bf16 per thread
            uint32_t val = *(const uint32_t*)&Tlds[row][col2 * 2];
            *(uint32_t*)(YpT + ((size_t)b * 81 + sp) * CC + cblk * 128 + col2 * 2) = val;
        }
    }
}

// ---------- direct conv GEMM: M=2048(co), N=128/block(2 batches x 64), K=18432 tap-major ----------
// B-tiles gathered on the fly from YpT (halo rows give zero padding). split-K z=2.
// grid 512 = xcd-swizzled (z2 x co16 x bp16), 512 threads (8 waves of 32co x 64n).
__global__ __launch_bounds__(512, 4) void conv_kernel(
    const bf16* __restrict__ Wr, const bf16* __restrict__ YpT, float* __restrict__ partials)
{
    __shared__ bf16 Asub[128 * 64];
    __shared__ bf16 Bsub[128 * 64];
    const int tid = threadIdx.x;
    const int w = tid >> 6, l = tid & 63;
    const int lhi = l >> 4, llo = l & 15;
    const int wm = w >> 1, wn = w & 1;          // wave tile: 32 co x 64 n

    uint32_t g = blockIdx.x;
    uint32_t xcd = g & 7u, t2 = g >> 3;          // t2 in [0,64)
    uint32_t pair = xcd * 4u + (t2 >> 4);        // [0,32): (z,co-block), 4 pairs per XCD
    uint32_t bp = t2 & 15u;                      // batch pair
    uint32_t z = pair >> 4, mt = pair & 15u;
    uint32_t b0 = bp * 2u;

    // per-thread staging geometry (loop-invariant)
    uint32_t eo0 = (uint32_t)tid * 8u;           // element offset in tile, +4096 for i=1
    uint32_t rowA0 = eo0 >> 6, colA = eo0 & 63u; // 8 lanes per 64-elem row
    const bf16* gaBase[2];
    const bf16* gbRow[2];
    uint32_t spBase[2]; bool live[2];
#pragma unroll
    for (int i = 0; i < 2; i++) {
        uint32_t row = rowA0 + i * 64u;
        gaBase[i] = Wr + (size_t)(mt * 128u + row) * K9 + colA;
        uint32_t bl = row >> 6, r2 = row & 63u;
        live[i] = (r2 < 49u);
        spBase[i] = live[i] ? (r2 + 2u * (r2 / 7u)) : 0u;
        gbRow[i] = YpT + (size_t)(b0 + bl) * 81u * CC + colA;
    }

    f32x4 acc[2][4];
#pragma unroll
    for (int fm = 0; fm < 2; fm++)
#pragma unroll
        for (int fn = 0; fn < 4; fn++) acc[fm][fn] = (f32x4){0, 0, 0, 0};

    for (int ktl = 0; ktl < 144; ktl++) {
        uint32_t kt = z * 144u + (uint32_t)ktl;
        uint32_t tap = kt >> 5, ci0 = (kt & 31u) * 64u;
        uint32_t tapoff = (tap / 3u) * 9u + (tap % 3u);
        uint32_t kb = tap * 2048u + ci0;
#pragma unroll
        for (int i = 0; i < 2; i++) {
            const bf16* ga = gaBase[i] + kb;
            uint32_t sp = live[i] ? (spBase[i] + tapoff) : 0u;
            const bf16* gb = gbRow[i] + (size_t)sp * CC + ci0;
            GLOAD_LDS(ga, (char*)Asub + tid * 16 + i * 8192);
            GLOAD_LDS(gb, (char*)Bsub + tid * 16 + i * 8192);
        }
        __syncthreads();
#pragma unroll
        for (int kk = 0; kk < 2; kk++) {
            bf16x8 af[2], bfr[4];
#pragma unroll
            for (int f = 0; f < 2; f++)
                af[f] = *(const bf16x8*)&Asub[(wm * 32 + f * 16 + llo) * 64 + kk * 32 + lhi * 8];
#pragma unroll
            for (int f = 0; f < 4; f++)
                bfr[f] = *(const bf16x8*)&Bsub[(wn * 64 + f * 16 + llo) * 64 + kk * 32 + lhi * 8];
#pragma unroll
            for (int fm = 0; fm < 2; fm++)
#pragma unroll
                for (int fn = 0; fn < 4; fn++)
                    acc[fm][fn] = MFMA(af[fm], bfr[fn], acc[fm][fn]);
        }
        __syncthreads();
    }
    // partials [z][co 2048][b 32][n 64]
#pragma unroll
    for (int fm = 0; fm < 2; fm++)
#pragma unroll
        for (int fn = 0; fn < 4; fn++)
#pragma unroll
            for (int r = 0; r < 4; r++) {
                uint32_t co = mt * 128u + (uint32_t)(wm * 32 + fm * 16 + lhi * 4 + r);
                uint32_t n = (uint32_t)(wn * 64 + fn * 16 + llo);
                uint32_t b = b0 + (n >> 6), p = n & 63u;
                partials[(((size_t)z * 2048u + co) * 32u + b) * 64u + p] = acc[fm][fn][r];
            }
}

// ---------- reduce: out = p0 + p1 + bias + residual ----------
__global__ void reduce_kernel(const float* __restrict__ partials, const float* __restrict__ x,
                              const float* __restrict__ cb, float* __restrict__ out)
{
    uint32_t idx = blockIdx.x * 256u + threadIdx.x;   // [b][c][p], 32*2048*49
    uint32_t p = idx % 49u;
    uint32_t c = (idx / 49u) & 2047u;
    uint32_t b = idx / (49u * 2048u);
    size_t base = ((size_t)c * 32u + b) * 64u + p;
    float s = cb[c] + x[idx] + partials[base] + partials[4194304u + base];
    out[idx] = s;
}

extern "C" void kernel_launch(void* const* d_in, const int* in_sizes, int n_in,
                              void* d_out, int out_size, void* d_ws, size_t ws_size,
                              hipStream_t stream) {
    (void)in_sizes; (void)n_in; (void)out_size; (void)ws_size;
    const float* x = (const float*)d_in[0];
    const float* cw = (const float*)d_in[1];
    const float* cb = (const float*)d_in[2];
    float* out = (float*)d_out;
    char* ws = (char*)d_ws;

    bf16* xb   = (bf16*)(ws);                    //  8,388,608 B
    bf16* xbT  = (bf16*)(ws + 8388608);          //  8,388,608 B
    bf16* Wr   = (bf16*)(ws + 16777216);         // 75,497,472 B
    bf16* YpT  = (bf16*)(ws + 92274688);         // 10,616,832 B
    float* partials = (float*)(ws + 102891520);  // 33,554,432 B (total 136,445,952)

    prep_xb_kernel<<<16384, 256, 0, stream>>>(x, xb);
    prep_xbT_kernel<<<16384, 256, 0, stream>>>(x, xbT);
    castw_kernel<<<4096, 256, 0, stream>>>(cw, Wr);
    zero_ypt_kernel<<<2592, 256, 0, stream>>>((u32x4*)YpT);
    attn_kernel<<<512, 256, 0, stream>>>(xb, xbT, YpT);
    conv_kernel<<<512, 512, 0, stream>>>(Wr, YpT, partials);
    reduce_kernel<<<12544, 256, 0, stream>>>(partials, x, cb, out);
}

// Round 4
// 356.866 us; speedup vs baseline: 1.4249x; 1.2325x over previous
//
#include <hip/hip_runtime.h>
#include <stdint.h>

#define BB 32
#define CC 2048
#define NPIX 49
#define KPAD 64
#define K9 18432      // CC*9 (k = tap*2048 + ci, tap-major)
#define ZROWS 2624    // 32*81 interior+halo rows + 32 guard rows (zero)
#define NP 1792       // dense n padded (14*128)

typedef __bf16 bf16;
typedef __bf16 bf16x4 __attribute__((ext_vector_type(4)));
typedef __bf16 bf16x8 __attribute__((ext_vector_type(8)));
typedef float f32x4 __attribute__((ext_vector_type(4)));
typedef uint32_t u32x4 __attribute__((ext_vector_type(4)));

#define MFMA(a,b,c) __builtin_amdgcn_mfma_f32_16x16x32_bf16(a,b,c,0,0,0)
#define GLOAD_LDS(g, l) __builtin_amdgcn_global_load_lds( \
    (const __attribute__((address_space(1))) void*)(g),   \
    (__attribute__((address_space(3))) void*)(l), 16, 0, 0)

// ---------- prep: x -> xb [B][C][64] bf16 (K padded 49->64 with zeros) ----------
__global__ void prep_xb_kernel(const float* __restrict__ x, bf16* __restrict__ xb) {
    uint32_t idx = blockIdx.x * 256u + threadIdx.x;
    uint32_t n = idx & 63u, bc = idx >> 6;
    float v = (n < 49u) ? x[bc * 49u + n] : 0.f;
    xb[idx] = (bf16)v;
}

// ---------- prep: x -> xbT [B][64][C] bf16 ----------
__global__ void prep_xbT_kernel(const float* __restrict__ x, bf16* __restrict__ xbT) {
    uint32_t idx = blockIdx.x * 256u + threadIdx.x;
    uint32_t c = idx & 2047u, n = (idx >> 11) & 63u, b = idx >> 17;
    float v = (n < 49u) ? x[(b * 2048u + c) * 49u + n] : 0.f;
    xbT[idx] = (bf16)v;
}

// ---------- prep: conv_w [co][ci][3][3] f32 -> Wr [co][t][ci] bf16 (tap-major K) ----------
__global__ void castw_kernel(const float* __restrict__ cw, bf16* __restrict__ Wr) {
    uint32_t t = blockIdx.x * 256u + threadIdx.x;   // 2048*512
    uint32_t q = t & 511u, co = t >> 9;
    uint32_t ci0 = q * 4u;
    const float* src = cw + ((size_t)co * 2048u + ci0) * 9u;
    float v[4][9];
#pragma unroll
    for (int c = 0; c < 4; c++)
#pragma unroll
        for (int tt = 0; tt < 9; tt++) v[c][tt] = src[c * 9 + tt];
    bf16* dst = Wr + (size_t)co * K9 + ci0;
#pragma unroll
    for (int tt = 0; tt < 9; tt++) {
        bf16x4 o;
        o[0] = (bf16)v[0][tt]; o[1] = (bf16)v[1][tt];
        o[2] = (bf16)v[2][tt]; o[3] = (bf16)v[3][tt];
        *(bf16x4*)(dst + (size_t)tt * 2048u) = o;
    }
}

// ---------- prep: zero YpT [ZROWS][C] bf16 (halo + guard rows must stay 0) ----------
__global__ void zero_ypt_kernel(u32x4* __restrict__ YpT) {
    YpT[blockIdx.x * 256u + threadIdx.x] = (u32x4){0, 0, 0, 0};
}

// ---------- fused bilinear -> softmax -> Y, writing YpT[b][sp][c] (transposed, padded) ----------
__global__ __launch_bounds__(256, 2) void attn_kernel(
    const bf16* __restrict__ xb, const bf16* __restrict__ xbT, bf16* __restrict__ YpT)
{
    __shared__ __align__(16) char smem_raw[34816];
    bf16 (*Plds)[32][136] = reinterpret_cast<bf16(*)[32][136]>(smem_raw);
    bf16 (*Tlds)[132]     = reinterpret_cast<bf16(*)[132]>(smem_raw);
    const int tid = threadIdx.x;
    const int w = tid >> 6, l = tid & 63;
    const int lhi = l >> 4, llo = l & 15;
    const int b = blockIdx.x >> 4, cblk = blockIdx.x & 15;
    const int c0 = cblk * 128 + w * 32;
    const bf16* xbB = xb + (size_t)b * CC * KPAD;
    const bf16* xbTB = xbT + (size_t)b * KPAD * CC;

    bf16x8 aQ[2][2];
#pragma unroll
    for (int cf = 0; cf < 2; cf++)
#pragma unroll
        for (int kk = 0; kk < 2; kk++)
            aQ[cf][kk] = *(const bf16x8*)(xbB + (uint32_t)(c0 + cf * 16 + llo) * KPAD + kk * 32 + lhi * 8);

    f32x4 accY[2][4];
#pragma unroll
    for (int cf = 0; cf < 2; cf++)
#pragma unroll
        for (int nf = 0; nf < 4; nf++) accY[cf][nf] = (f32x4){0, 0, 0, 0};
    float rowsum[2][4] = {};

    for (int dt = 0; dt < 16; dt++) {
        const int d0 = dt * 128;
        f32x4 accS[2][8];
#pragma unroll
        for (int cf = 0; cf < 2; cf++)
#pragma unroll
            for (int df = 0; df < 8; df++) accS[cf][df] = (f32x4){0, 0, 0, 0};
#pragma unroll
        for (int kk = 0; kk < 2; kk++) {
#pragma unroll
            for (int df = 0; df < 8; df++) {
                bf16x8 bK = *(const bf16x8*)(xbB + (uint32_t)(d0 + df * 16 + llo) * KPAD + kk * 32 + lhi * 8);
                accS[0][df] = MFMA(aQ[0][kk], bK, accS[0][df]);
                accS[1][df] = MFMA(aQ[1][kk], bK, accS[1][df]);
            }
        }
#pragma unroll
        for (int cf = 0; cf < 2; cf++)
#pragma unroll
            for (int df = 0; df < 8; df++)
#pragma unroll
                for (int r = 0; r < 4; r++) {
                    float p = __expf(accS[cf][df][r] * (-1.0f / 49.0f));
                    rowsum[cf][r] += p;
                    Plds[w][cf * 16 + lhi * 4 + r][df * 16 + llo] = (bf16)p;
                }
        __syncthreads();
#pragma unroll
        for (int kk2 = 0; kk2 < 4; kk2++) {
            bf16x8 aP[2];
#pragma unroll
            for (int cf = 0; cf < 2; cf++)
                aP[cf] = *(const bf16x8*)&Plds[w][cf * 16 + llo][kk2 * 32 + lhi * 8];
#pragma unroll
            for (int nf = 0; nf < 4; nf++) {
                bf16x8 bV = *(const bf16x8*)(xbTB + (uint32_t)(nf * 16 + llo) * CC + d0 + kk2 * 32 + lhi * 8);
                accY[0][nf] = MFMA(aP[0], bV, accY[0][nf]);
                accY[1][nf] = MFMA(aP[1], bV, accY[1][nf]);
            }
        }
        __syncthreads();
    }
#pragma unroll
    for (int cf = 0; cf < 2; cf++)
#pragma unroll
        for (int r = 0; r < 4; r++) {
            float s = rowsum[cf][r];
            s += __shfl_xor(s, 1);
            s += __shfl_xor(s, 2);
            s += __shfl_xor(s, 4);
            s += __shfl_xor(s, 8);
            rowsum[cf][r] = 1.0f / s;
        }
#pragma unroll
    for (int cf = 0; cf < 2; cf++)
#pragma unroll
        for (int nf = 0; nf < 4; nf++)
#pragma unroll
            for (int r = 0; r < 4; r++) {
                int n = nf * 16 + llo;
                int cl = w * 32 + cf * 16 + lhi * 4 + r;
                Tlds[n][cl] = (bf16)(accY[cf][nf][r] * rowsum[cf][r]);
            }
    __syncthreads();
#pragma unroll
    for (int rr = 0; rr < 13; rr++) {
        int row = rr * 4 + (tid >> 6);
        if (row < NPIX) {
            int i = row / 7, j = row % 7;
            int sp = (i + 1) * 9 + (j + 1);
            int col2 = tid & 63;
            uint32_t val = *(const uint32_t*)&Tlds[row][col2 * 2];
            *(uint32_t*)(YpT + ((size_t)b * 81 + sp) * CC + cblk * 128 + col2 * 2) = val;
        }
    }
}

// ---------- direct conv GEMM: M=2048(co), N=1792 dense n, K=18432, splitK=2 ----------
// 448 blocks (xcd-grouped by (z,mt) A-panel), 512 thr = 8 waves of 64co x 32n.
// T2 XOR-swizzle: linear gload_lds dest + inverse-swizzled global src + swizzled ds_read.
__global__ __launch_bounds__(512, 4) void conv_kernel(
    const bf16* __restrict__ Wr, const bf16* __restrict__ YpT, float* __restrict__ partials)
{
    __shared__ bf16 Asub[128 * 64];
    __shared__ bf16 Bsub[128 * 64];
    const int tid = threadIdx.x;
    const int w = tid >> 6, l = tid & 63;
    const int lhi = l >> 4, llo = l & 15;
    const int wm = w >> 2, wn = w & 3;           // wave tile: 64 co x 32 n

    uint32_t g = blockIdx.x;
    uint32_t xcd = g & 7u, inner = g >> 3;       // inner in [0,56)
    uint32_t pairIdx = xcd * 4u + inner / 14u;   // [0,32): (z,mt) grouped per XCD
    uint32_t nt = inner % 14u;
    uint32_t z = pairIdx >> 4, mt = pairIdx & 15u;

    // staging geometry: slot i: linear LDS byte p = i*8192 + tid*16
    uint32_t kb16 = tid & 7u;                    // 16B-slot within 128B row
    uint32_t row0 = tid >> 3;                    // row [0,64), +64 for slot 1 ((row&7) unchanged)
    uint32_t srcK = (kb16 ^ (row0 & 7u)) << 3;   // inverse-swizzled element offset [0,64)

    const bf16* gaBase[2];
    const bf16* gbBase[2];
#pragma unroll
    for (int i = 0; i < 2; i++) {
        uint32_t row = row0 + (uint32_t)i * 64u;
        gaBase[i] = Wr + (size_t)(mt * 128u + row) * K9 + (size_t)z * 9216u + srcK;
        uint32_t n = nt * 128u + row;
        uint32_t rowIdx;
        if (n < 1568u) {
            uint32_t b = n / 49u, p = n % 49u;
            uint32_t i2 = p / 7u, j2 = p % 7u;
            rowIdx = b * 81u + (i2 + 1u) * 9u + (j2 + 1u);
        } else rowIdx = 2602u;                   // guard: rowIdx+tapoff stays in zeroed [2592,2624)
        gbBase[i] = YpT + (size_t)rowIdx * 2048u + srcK;
    }

    f32x4 acc[4][2];
#pragma unroll
    for (int fm = 0; fm < 4; fm++)
#pragma unroll
        for (int fn = 0; fn < 2; fn++) acc[fm][fn] = (f32x4){0, 0, 0, 0};

    for (int ktl = 0; ktl < 144; ktl++) {
        uint32_t kt = z * 144u + (uint32_t)ktl;
        uint32_t tap = kt >> 5, ci0 = (kt & 31u) << 6;
        int tapoff = (int)(tap / 3u) * 9 + (int)(tap % 3u) - 10;
        uint32_t kbA = (uint32_t)ktl * 64u;
#pragma unroll
        for (int i = 0; i < 2; i++) {
            GLOAD_LDS(gaBase[i] + kbA, (char*)Asub + i * 8192 + tid * 16);
            GLOAD_LDS(gbBase[i] + (int)ci0 + tapoff * 2048, (char*)Bsub + i * 8192 + tid * 16);
        }
        __syncthreads();
#pragma unroll
        for (int kk = 0; kk < 2; kk++) {
            bf16x8 af[4], bfr[2];
#pragma unroll
            for (int f = 0; f < 4; f++) {
                uint32_t r = (uint32_t)(wm * 64 + f * 16 + llo);
                uint32_t bo = r * 128u + ((((uint32_t)(kk * 4 + lhi)) ^ (r & 7u)) << 4);
                af[f] = *(const bf16x8*)((const char*)Asub + bo);
            }
#pragma unroll
            for (int f = 0; f < 2; f++) {
                uint32_t r = (uint32_t)(wn * 32 + f * 16 + llo);
                uint32_t bo = r * 128u + ((((uint32_t)(kk * 4 + lhi)) ^ (r & 7u)) << 4);
                bfr[f] = *(const bf16x8*)((const char*)Bsub + bo);
            }
#pragma unroll
            for (int fm = 0; fm < 4; fm++)
#pragma unroll
                for (int fn = 0; fn < 2; fn++)
                    acc[fm][fn] = MFMA(af[fm], bfr[fn], acc[fm][fn]);
        }
        __syncthreads();
    }
    // partials [z][co 2048][n 1792]
    float* pz = partials + (size_t)z * 2048u * NP;
    uint32_t co0 = mt * 128u + (uint32_t)(wm * 64 + lhi * 4);
    uint32_t n0 = nt * 128u + (uint32_t)(wn * 32 + llo);
#pragma unroll
    for (int fm = 0; fm < 4; fm++)
#pragma unroll
        for (int fn = 0; fn < 2; fn++)
#pragma unroll
            for (int r = 0; r < 4; r++)
                pz[(size_t)(co0 + fm * 16u + r) * NP + (n0 + fn * 16u)] = acc[fm][fn][r];
}

// ---------- reduce: out = p0 + p1 + bias + residual ----------
__global__ void reduce_kernel(const float* __restrict__ partials, const float* __restrict__ x,
                              const float* __restrict__ cb, float* __restrict__ out)
{
    uint32_t idx = blockIdx.x * 256u + threadIdx.x;   // [b][c][p], 32*2048*49
    uint32_t p = idx % 49u;
    uint32_t c = (idx / 49u) & 2047u;
    uint32_t b = idx / (49u * 2048u);
    uint32_t n = b * 49u + p;
    size_t base = (size_t)c * NP + n;
    out[idx] = cb[c] + x[idx] + partials[base] + partials[(size_t)2048u * NP + base];
}

extern "C" void kernel_launch(void* const* d_in, const int* in_sizes, int n_in,
                              void* d_out, int out_size, void* d_ws, size_t ws_size,
                              hipStream_t stream) {
    (void)in_sizes; (void)n_in; (void)out_size; (void)ws_size;
    const float* x = (const float*)d_in[0];
    const float* cw = (const float*)d_in[1];
    const float* cb = (const float*)d_in[2];
    float* out = (float*)d_out;
    char* ws = (char*)d_ws;

    bf16* xb   = (bf16*)(ws);                    //   8,388,608 B
    bf16* xbT  = (bf16*)(ws + 8388608);          //   8,388,608 B
    bf16* Wr   = (bf16*)(ws + 16777216);         //  75,497,472 B
    bf16* YpT  = (bf16*)(ws + 92274688);         //  10,747,904 B (2624 rows x 2048 x 2B)
    float* partials = (float*)(ws + 103022592);  //  29,360,128 B (total 132,382,720)

    prep_xb_kernel<<<16384, 256, 0, stream>>>(x, xb);
    prep_xbT_kernel<<<16384, 256, 0, stream>>>(x, xbT);
    castw_kernel<<<4096, 256, 0, stream>>>(cw, Wr);
    zero_ypt_kernel<<<2624, 256, 0, stream>>>((u32x4*)YpT);
    attn_kernel<<<512, 256, 0, stream>>>(xb, xbT, YpT);
    conv_kernel<<<448, 512, 0, stream>>>(Wr, YpT, partials);
    reduce_kernel<<<12544, 256, 0, stream>>>(partials, x, cb, out);
}